// Round 2
// baseline (3989.758 us; speedup 1.0000x reference)
//
#include <hip/hip_runtime.h>
#include <math.h>

#define B_ 4
#define L_ 4096
#define D_ 512
#define P_ 128
#define V_ 8
#define N_ (B_*L_)
#define NC 64               // chunks per batch for scans
#define CL (L_/NC)          // 64 positions per chunk
#define LD ((size_t)L_*D_)  // per-batch plane: 2,097,152 elems

__device__ __forceinline__ float geluf(float v){
    return 0.5f*v*(1.0f+erff(v*0.7071067811865475f));
}

// ---------------- generic tiled fp32 GEMM (per-batch, 4096 rows) ----------------
// A given as up to 4 segments, each [L_,512] row-major; k selects segment via k>>9.
// W row-major [K,M]. C -> C0 (ld=M) or split planes C0/C1 (ld=512) when C1!=0.
// Epilogue: bias -> act -> colscale -> |*sscalep| -> *mulbuf -> +addbuf.
__global__ __launch_bounds__(256)
void gemm_k(const float* __restrict__ A0, const float* __restrict__ A1,
            const float* __restrict__ A2, const float* __restrict__ A3,
            const float* __restrict__ W, const float* __restrict__ bias,
            float* __restrict__ C0, float* __restrict__ C1,
            int K, int M, int act,
            const float* __restrict__ colscale, const float* __restrict__ sscalep,
            const float* __restrict__ mulbuf, const float* __restrict__ addbuf)
{
    __shared__ __align__(16) float As[16][68];
    __shared__ __align__(16) float Ws[16][68];
    const float* Aseg[4] = {A0,A1,A2,A3};
    const int tid = threadIdx.x;
    const int tx = tid & 15, ty = tid >> 4;
    const int row0 = blockIdx.y * 64, col0 = blockIdx.x * 64;
    const int lm = tid >> 2, lk = (tid & 3) * 4;
    const int wk = tid >> 4, wc = (tid & 15) * 4;
    float acc[4][4] = {};
    for (int kt = 0; kt < K; kt += 16) {
        int kg = kt + lk;
        const float* ap = Aseg[kg >> 9] + (size_t)(row0 + lm) * 512 + (kg & 511);
        float4 a4 = *(const float4*)ap;
        As[lk+0][lm]=a4.x; As[lk+1][lm]=a4.y; As[lk+2][lm]=a4.z; As[lk+3][lm]=a4.w;
        float4 w4 = *(const float4*)(W + (size_t)(kt+wk)*M + col0 + wc);
        *(float4*)&Ws[wk][wc] = w4;
        __syncthreads();
        #pragma unroll
        for (int kk = 0; kk < 16; ++kk) {
            float4 av = *(const float4*)&As[kk][ty*4];
            float4 bv = *(const float4*)&Ws[kk][tx*4];
            float a_[4]={av.x,av.y,av.z,av.w};
            float b_[4]={bv.x,bv.y,bv.z,bv.w};
            #pragma unroll
            for (int i=0;i<4;i++)
                #pragma unroll
                for (int j=0;j<4;j++) acc[i][j] = fmaf(a_[i], b_[j], acc[i][j]);
        }
        __syncthreads();
    }
    float ss = sscalep ? fabsf(*sscalep) : 1.0f;
    #pragma unroll
    for (int i=0;i<4;i++){
        int r = row0 + ty*4 + i;
        #pragma unroll
        for (int j=0;j<4;j++){
            int c = col0 + tx*4 + j;
            float t = acc[i][j] + bias[c];
            if (act==1) t = geluf(t);
            else if (act==2) t = 1.0f/(1.0f+expf(-t));
            else if (act==3) t = tanhf(t)*3.14159265358979323846f;
            if (colscale) t *= fabsf(colscale[c]);
            t *= ss;
            if (mulbuf) t *= mulbuf[(size_t)r*M + c];
            if (addbuf) t += addbuf[(size_t)r*512 + c];
            if (C1) {
                if (c < 512) C0[(size_t)r*512 + c] = t;
                else         C1[(size_t)r*512 + (c-512)] = t;
            } else {
                C0[(size_t)r*M + c] = t;
            }
        }
    }
}

// ---------------- scans (per-batch) ----------------
// chunk sums of omega_scaled and x
__global__ __launch_bounds__(256)
void s1a_k(const float* __restrict__ omega, const float* __restrict__ xb,
           float* __restrict__ csA, float* __restrict__ csX)
{
    int bid = blockIdx.x;                 // NC*2
    int dg = bid & 1, c = bid >> 1;
    int d = dg*256 + threadIdx.x;
    size_t base = (size_t)(c*CL)*D_ + d;
    float sA=0.f, sX=0.f;
    for (int l=0;l<CL;l++){
        sA += omega[base + (size_t)l*D_];
        sX += xb[base + (size_t)l*D_];
    }
    size_t ci = (size_t)c*D_ + d;
    csA[ci]=sA; csX[ci]=sX;
}

// exclusive prefix over chunk dim for up to 3 [NC,D] arrays
__global__ void prefix_k(float* a, float* b2, float* c3, int nbuf)
{
    int d = blockIdx.x*blockDim.x + threadIdx.x;
    if (d >= D_) return;
    float* bufs[3] = {a,b2,c3};
    for (int i=0;i<nbuf;i++){
        float* p = bufs[i] + d;
        float run=0.f;
        for (int c=0;c<NC;c++){
            float v = p[(size_t)c*D_];
            p[(size_t)c*D_] = run;
            run += v;
        }
    }
}

// replay: phi = phi_init + cumsum(omega) (stored); ctx = xcum/pos;
// chunk sums of magnitude, wv1*cos(phi), wv1*sin(phi)
__global__ __launch_bounds__(256)
void s1c_k(const float* __restrict__ omega, const float* __restrict__ xb,
           const float* __restrict__ phi_init,
           const float* __restrict__ magn, const float* __restrict__ wv1,
           const float* __restrict__ csA, const float* __restrict__ csX,
           float* __restrict__ phi, float* __restrict__ ctx,
           float* __restrict__ csM, float* __restrict__ csC, float* __restrict__ csS)
{
    int bid = blockIdx.x;
    int dg = bid & 1, c = bid >> 1;
    int d = dg*256 + threadIdx.x;
    size_t ci = (size_t)c*D_ + d;
    float phiacc = csA[ci], xacc = csX[ci];
    float sM=0.f,sC=0.f,sS=0.f;
    size_t base = (size_t)(c*CL)*D_ + d;
    for (int l=0;l<CL;l++){
        size_t idx = base + (size_t)l*D_;
        phiacc += omega[idx];
        float ph = phi_init[idx] + phiacc;
        phi[idx] = ph;
        float spv, cpv; sincosf(ph, &spv, &cpv);
        xacc += xb[idx];
        ctx[idx] = xacc / (float)(c*CL + l + 1);
        float m = magn[idx]; sM += m;
        float w = wv1[idx];
        sC = fmaf(w, cpv, sC); sS = fmaf(w, spv, sS);
    }
    csM[ci]=sM; csC[ci]=sC; csS[ci]=sS;
}

// replay mem1 cumsums -> pos_ret (recompute sincos(phi), sincos(phi+qoff))
__global__ __launch_bounds__(256)
void s1e_k(const float* __restrict__ magn, const float* __restrict__ wv1,
           const float* __restrict__ qoff, const float* __restrict__ phi,
           const float* __restrict__ csM, const float* __restrict__ csC,
           const float* __restrict__ csS, float* __restrict__ pos_ret)
{
    int bid = blockIdx.x;
    int dg = bid & 1, c = bid >> 1;
    int d = dg*256 + threadIdx.x;
    size_t ci = (size_t)c*D_ + d;
    float mA=csM[ci], cA=csC[ci], sA=csS[ci];
    size_t base = (size_t)(c*CL)*D_ + d;
    for (int l=0;l<CL;l++){
        size_t idx = base + (size_t)l*D_;
        mA += magn[idx];
        float w = wv1[idx];
        float ph = phi[idx];
        float spv, cpv; sincosf(ph, &spv, &cpv);
        cA = fmaf(w, cpv, cA); sA = fmaf(w, spv, sA);
        float rs = rsqrtf(mA + 1e-8f);
        float sq, cq; sincosf(ph + qoff[idx], &sq, &cq);
        pos_ret[idx] = (cA*cq + sA*sq) * rs * 0.04419417382415922f; // 1/sqrt(512)
    }
}

// values (D->8) and store_gate (D->1): one wave per row
__global__ __launch_bounds__(256)
void vencsg_k(const float* __restrict__ xb, const float* __restrict__ Wv,
              const float* __restrict__ bv, const float* __restrict__ Wg,
              const float* __restrict__ bg,
              float* __restrict__ vals, float* __restrict__ sgate)
{
    int gw = (int)((blockIdx.x*(size_t)blockDim.x + threadIdx.x) >> 6);
    int lane = threadIdx.x & 63;
    const float* xr = xb + (size_t)gw*D_;
    float pv[8] = {0,0,0,0,0,0,0,0}; float pg = 0.f;
    #pragma unroll
    for (int j=0;j<8;j++){
        int k = lane + 64*j;
        float xv = xr[k];
        #pragma unroll
        for (int v=0;v<8;v++) pv[v] = fmaf(xv, Wv[k*8+v], pv[v]);
        pg = fmaf(xv, Wg[k], pg);
    }
    #pragma unroll
    for (int off=32; off>0; off>>=1){
        #pragma unroll
        for (int v=0;v<8;v++) pv[v] += __shfl_down(pv[v], off, 64);
        pg += __shfl_down(pg, off, 64);
    }
    if (lane==0){
        #pragma unroll
        for (int v=0;v<8;v++) vals[(size_t)gw*8+v] = pv[v] + bv[v];
        sgate[gw] = 1.0f/(1.0f+expf(-(pg + bg[0])));
    }
}

// KV scan chunk sums
__global__ __launch_bounds__(256)
void s2a_k(const float* __restrict__ spb, const float* __restrict__ vals,
           const float* __restrict__ sgate,
           float* __restrict__ csKV, float* __restrict__ csG)
{
    int c = blockIdx.x;                   // NC
    int t = threadIdx.x; int p = t & 127; int vb = (t>>7)*4;
    size_t nbase = (size_t)c*CL;
    float ac[4]={0,0,0,0}, as[4]={0,0,0,0}; float g=0.f;
    for (int l=0;l<CL;l++){
        size_t n = nbase + l;
        float sph = spb[n*(size_t)P_ + p];
        float ssn, sc; sincosf(sph, &ssn, &sc);
        float sg = sgate[n];
        #pragma unroll
        for (int j=0;j<4;j++){
            float gv = vals[n*(size_t)V_ + vb + j] * sg;
            ac[j] = fmaf(sc, gv, ac[j]);
            as[j] = fmaf(ssn, gv, as[j]);
        }
        g += sg;
    }
    float* base = csKV + (size_t)c*2048;
    #pragma unroll
    for (int j=0;j<4;j++){
        base[p*V_ + vb + j] = ac[j];
        base[1024 + p*V_ + vb + j] = as[j];
    }
    if (t==0) csG[c] = g;
}

__global__ void s2b_k(float* csKV, float* csG)
{
    int t = blockIdx.x*blockDim.x + threadIdx.x;  // 8 blocks x 256 = 2048
    if (t < 2048){
        float* ptr = csKV + t;
        float run=0.f;
        for (int c=0;c<NC;c++){
            float v = ptr[(size_t)c*2048];
            ptr[(size_t)c*2048]=run;
            run+=v;
        }
    }
    if (t == 0){
        float run=0.f;
        for (int c=0;c<NC;c++){ float v=csG[c]; csG[c]=run; run+=v; }
    }
}

// KV scan replay + fused retrieval
__global__ __launch_bounds__(256)
void s2c_k(const float* __restrict__ spb, const float* __restrict__ vals,
           const float* __restrict__ sgate, const float* __restrict__ qp,
           const float* __restrict__ csKV, const float* __restrict__ csG,
           float* __restrict__ kvret)
{
    __shared__ float part[4][4];
    int c = blockIdx.x;
    int t = threadIdx.x; int p = t & 127; int vg = t >> 7; int vb = vg*4;
    int wave = t >> 6, lane = t & 63;
    size_t nbase = (size_t)c*CL;
    const float* kvb = csKV + (size_t)c*2048;
    float stc[4], sts[4];
    #pragma unroll
    for (int j=0;j<4;j++){ stc[j] = kvb[p*V_+vb+j]; sts[j] = kvb[1024 + p*V_+vb+j]; }
    float gacc = csG[c];
    for (int l=0;l<CL;l++){
        size_t n = nbase + l;
        float sph = spb[n*(size_t)P_ + p];
        float ssn, sc; sincosf(sph, &ssn, &sc);
        float sg = sgate[n]; gacc += sg;
        #pragma unroll
        for (int j=0;j<4;j++){
            float gv = vals[n*(size_t)V_ + vb + j]*sg;
            stc[j] = fmaf(sc, gv, stc[j]);
            sts[j] = fmaf(ssn, gv, sts[j]);
        }
        float qph = qp[n*(size_t)P_ + p];
        float qs, qc; sincosf(qph, &qs, &qc);
        float r[4];
        #pragma unroll
        for (int j=0;j<4;j++) r[j] = qc*stc[j] + qs*sts[j];
        #pragma unroll
        for (int off=1; off<64; off<<=1){
            #pragma unroll
            for (int j=0;j<4;j++) r[j] += __shfl_xor(r[j], off, 64);
        }
        if (lane==0){
            part[wave][0]=r[0]; part[wave][1]=r[1]; part[wave][2]=r[2]; part[wave][3]=r[3];
        }
        __syncthreads();
        if (t < 8){
            int v = t, vgg = v>>2, jj = v&3;
            float s = part[vgg*2][jj] + part[vgg*2+1][jj];
            float gc = fmaxf(gacc, 1.0f);
            kvret[n*(size_t)V_ + v] = s * rsqrtf(gc) * 0.08838834764831845f; // 1/sqrt(128)
        }
        __syncthreads();
    }
}

// kv_out = kvret @ W_kvo + b  (V=8 -> D)
__global__ __launch_bounds__(256)
void kvo_k(const float* __restrict__ kvret, const float* __restrict__ Wkvo,
           const float* __restrict__ bkvo, float* __restrict__ kvout)
{
    size_t idx = (size_t)blockIdx.x*256 + threadIdx.x;
    size_t n = idx >> 9; int d = (int)(idx & 511);
    float s = bkvo[d];
    #pragma unroll
    for (int v=0;v<8;v++) s = fmaf(kvret[n*8+v], Wkvo[v*512 + d], s);
    kvout[idx] = s;
}

// combined + LayerNorm -> 4 normalized planes (sincos(phi) on the fly)
__global__ __launch_bounds__(256)
void cmb_k(const float* __restrict__ pos_out, const float* __restrict__ kv_out,
           const float* __restrict__ xb, const float* __restrict__ phi,
           const float* __restrict__ ln_g, const float* __restrict__ ln_b,
           float* __restrict__ p0, float* __restrict__ p1,
           float* __restrict__ p2, float* __restrict__ p3)
{
    __shared__ float red[8];
    int n = blockIdx.x; int t = threadIdx.x;
    int wave = t>>6, lane = t&63;
    float v_[8]; float sum=0.f, sumsq=0.f;
    #pragma unroll
    for (int i=0;i<8;i++){
        int cidx = t + i*256;
        int seg = cidx >> 9, cc = cidx & 511;
        size_t id = (size_t)n*D_ + cc;
        float v;
        if (seg==0) v = pos_out[id];
        else if (seg==1) v = kv_out[id];
        else {
            float sp, cp; sincosf(phi[id], &sp, &cp);
            v = xb[id] * ((seg==2) ? cp : sp);
        }
        v_[i]=v; sum += v; sumsq = fmaf(v,v,sumsq);
    }
    #pragma unroll
    for (int off=32; off>0; off>>=1){
        sum += __shfl_xor(sum, off, 64);
        sumsq += __shfl_xor(sumsq, off, 64);
    }
    if (lane==0){ red[wave]=sum; red[wave+4]=sumsq; }
    __syncthreads();
    float s = red[0]+red[1]+red[2]+red[3];
    float q = red[4]+red[5]+red[6]+red[7];
    float mu = s * (1.0f/2048.0f);
    float var = q * (1.0f/2048.0f) - mu*mu;
    float rstd = rsqrtf(var + 1e-5f);
    #pragma unroll
    for (int i=0;i<8;i++){
        int cidx = t + i*256;
        int seg = cidx >> 9, cc = cidx & 511;
        float h = (v_[i]-mu)*rstd*ln_g[cidx] + ln_b[cidx];
        float* pp = (seg==0)?p0:(seg==1)?p1:(seg==2)?p2:p3;
        pp[(size_t)n*D_ + cc] = h;
    }
}

// diagnostic fallback: out = x  (distinguishes "ws too small" in absmax signature)
__global__ void copyx_k(const float* __restrict__ x, float* __restrict__ out, size_t n)
{
    size_t i = (size_t)blockIdx.x*256 + threadIdx.x;
    if (i < n) out[i] = x[i];
}

extern "C" void kernel_launch(void* const* d_in, const int* in_sizes, int n_in,
                              void* d_out, int out_size, void* d_ws, size_t ws_size,
                              hipStream_t stream)
{
    const float* x        =(const float*)d_in[0];
    const float* W_omega  =(const float*)d_in[1];  const float* b_omega=(const float*)d_in[2];
    const float* omega_sc =(const float*)d_in[3];
    const float* W_pi1    =(const float*)d_in[4];  const float* b_pi1 =(const float*)d_in[5];
    const float* W_pi2    =(const float*)d_in[6];  const float* b_pi2 =(const float*)d_in[7];
    const float* W_m1v    =(const float*)d_in[8];  const float* b_m1v =(const float*)d_in[9];
    const float* W_m1o    =(const float*)d_in[10]; const float* b_m1o =(const float*)d_in[11];
    const float* W_mag    =(const float*)d_in[12]; const float* b_mag =(const float*)d_in[13];
    const float* mag_sc   =(const float*)d_in[14];
    const float* W_qoff   =(const float*)d_in[15]; const float* b_qoff=(const float*)d_in[16];
    const float* W_kenc   =(const float*)d_in[17]; const float* b_kenc=(const float*)d_in[18];
    const float* W_venc   =(const float*)d_in[19]; const float* b_venc=(const float*)d_in[20];
    const float* W_sk1    =(const float*)d_in[21]; const float* b_sk1 =(const float*)d_in[22];
    const float* W_sk2    =(const float*)d_in[23]; const float* b_sk2 =(const float*)d_in[24];
    const float* W_sg     =(const float*)d_in[25]; const float* b_sg  =(const float*)d_in[26];
    const float* W_kvo    =(const float*)d_in[27]; const float* b_kvo =(const float*)d_in[28];
    const float* ln_g     =(const float*)d_in[29]; const float* ln_b  =(const float*)d_in[30];
    const float* W_o1     =(const float*)d_in[31]; const float* b_o1  =(const float*)d_in[32];
    const float* W_o2     =(const float*)d_in[33]; const float* b_o2  =(const float*)d_in[34];
    float* out = (float*)d_out;

    float* ws = (float*)d_ws;
    size_t off = 0;
    auto alloc = [&](size_t nelem){ float* p = ws + off; off += nelem; return p; };
    // per-batch slots (reused across batches):
    float* a0 = alloc(LD);  // omega_scaled -> pos_ret -> sk1g -> plane0
    float* a1 = alloc(LD);  // magnitude -> kv_out
    float* a2 = alloc(LD);  // wv1 -> plane1
    float* a3 = alloc(LD);  // pi1g -> ctx -> plane2
    float* a4 = alloc(LD);  // phi_init -> pos_out -> h1b
    float* a5 = alloc(LD);  // qoff -> plane3
    float* a6 = alloc(LD);  // phi -> h1a
    float* qp   = alloc((size_t)L_*P_);
    float* spb  = alloc((size_t)L_*P_);
    float* vals = alloc((size_t)L_*V_);
    float* sgate= alloc(L_);
    float* kvret= alloc((size_t)L_*V_);
    float* csA = alloc((size_t)NC*D_);
    float* csX = alloc((size_t)NC*D_);
    float* csM = alloc((size_t)NC*D_);
    float* csC = alloc((size_t)NC*D_);
    float* csS = alloc((size_t)NC*D_);
    float* csKV= alloc((size_t)NC*2048);
    float* csG = alloc(NC);
    if (off * sizeof(float) > ws_size) {
        // diagnostic fallback: out = x (absmax will be ~1.9, not 5.7)
        copyx_k<<<dim3((unsigned)(((size_t)N_*D_ + 255)/256)), dim3(256), 0, stream>>>(x, out, (size_t)N_*D_);
        return;
    }

    dim3 blk(256);
    auto gemm = [&](const float* A0,const float* A1,const float* A2,const float* A3,
                    const float* W,const float* bias,float* C0,float* C1,int K,int M,int act,
                    const float* colscale,const float* sscale,const float* mul,const float* add){
        dim3 grid(M/64, L_/64);
        gemm_k<<<grid, blk, 0, stream>>>(A0,A1,A2,A3,W,bias,C0,C1,K,M,act,colscale,sscale,mul,add);
    };

    for (int b = 0; b < B_; ++b) {
        const float* xb = x + (size_t)b*LD;
        float* outb = out + (size_t)b*LD;

        // first-level projections from x
        gemm(xb,0,0,0, W_omega,b_omega, a0,0, 512,512,0, omega_sc,0,0,0);  // omega_scaled
        gemm(xb,0,0,0, W_mag,  b_mag,   a1,0, 512,512,2, 0,mag_sc,0,0);    // magnitude
        gemm(xb,0,0,0, W_m1v,  b_m1v,   a2,0, 512,512,0, 0,0,a1,0);        // wv1 = magn*(xW+b)
        gemm(xb,0,0,0, W_pi1,  b_pi1,   a3,0, 512,512,1, 0,0,0,0);         // gelu(x@W_pi1)
        gemm(a3,0,0,0, W_pi2,  b_pi2,   a4,0, 512,512,0, 0,0,0,0);         // phi_init
        gemm(xb,0,0,0, W_qoff, b_qoff,  a5,0, 512,512,0, 0,0,0,0);         // qoff
        gemm(xb,0,0,0, W_kenc, b_kenc,  qp,0, 512,128,3, 0,0,0,0);         // query_phase
        vencsg_k<<<dim3((L_*64)/256), blk, 0, stream>>>(xb, W_venc,b_venc, W_sg,b_sg, vals, sgate);

        // scan chain 1
        s1a_k<<<dim3(NC*2), blk, 0, stream>>>(a0, xb, csA, csX);
        prefix_k<<<dim3(2), blk, 0, stream>>>(csA, csX, (float*)0, 2);
        s1c_k<<<dim3(NC*2), blk, 0, stream>>>(a0, xb, a4, a1, a2, csA, csX, a6, a3, csM, csC, csS);
        prefix_k<<<dim3(2), blk, 0, stream>>>(csM, csC, csS, 3);
        s1e_k<<<dim3(NC*2), blk, 0, stream>>>(a1, a2, a5, a6, csM, csC, csS, a0); // a0 = pos_ret

        gemm(a0,0,0,0, W_m1o,b_m1o, a4,0, 512,512,0, 0,0,0,0);             // pos_out (a4)
        gemm(xb,a3,0,0, W_sk1,b_sk1, a0,0, 1024,512,1, 0,0,0,0);           // sk1g (a0)
        gemm(a0,0,0,0, W_sk2,b_sk2, spb,0, 512,128,3, 0,0,0,0);            // storage_phase

        // KV phasor scan
        s2a_k<<<dim3(NC), blk, 0, stream>>>(spb, vals, sgate, csKV, csG);
        s2b_k<<<dim3(8), blk, 0, stream>>>(csKV, csG);
        s2c_k<<<dim3(NC), blk, 0, stream>>>(spb, vals, sgate, qp, csKV, csG, kvret);
        kvo_k<<<dim3((unsigned)(LD/256)), blk, 0, stream>>>(kvret, W_kvo, b_kvo, a1); // kv_out (a1)

        // combined + LN -> 4 planes; then output MLP
        cmb_k<<<dim3(L_), blk, 0, stream>>>(a4, a1, xb, a6, ln_g, ln_b, a0, a2, a3, a5);
        gemm(a0,a2,a3,a5, W_o1,b_o1, a6,a4, 2048,1024,1, 0,0,0,0);         // h1 -> a6,a4
        gemm(a6,a4,0,0,   W_o2,b_o2, outb,0, 1024,512,0, 0,0,0,xb);        // out = x + ...
    }
}

// Round 3
// 2426.444 us; speedup vs baseline: 1.6443x; 1.6443x over previous
//
#include <hip/hip_runtime.h>
#include <math.h>

#define B_ 4
#define L_ 4096
#define D_ 512
#define P_ 128
#define V_ 8
#define N_ (B_*L_)
#define NC 64               // chunks per batch for scans
#define CL (L_/NC)          // 64 positions per chunk
#define LD ((size_t)L_*D_)  // per-batch plane elems
#define PI_F 3.14159265358979323846f

typedef unsigned short ushort;
typedef __attribute__((ext_vector_type(8))) short bh8;   // 8 bf16 in 4 VGPRs
typedef __attribute__((ext_vector_type(4))) float f4;

__device__ __forceinline__ float geluf(float v){
    return 0.5f*v*(1.0f+erff(v*0.7071067811865475f));
}
__device__ __forceinline__ ushort f2b(float f){
    union { float f; unsigned u; } v; v.f = f;
    unsigned r = (v.u + 0x7fffu + ((v.u >> 16) & 1u)) >> 16;
    return (ushort)r;
}
__device__ __forceinline__ float b2f(ushort h){
    union { unsigned u; float f; } v; v.u = ((unsigned)h) << 16;
    return v.f;
}

// ---------------- bf16 MFMA GEMM ----------------
// C[4096 x M] = A[4096 x K] @ W[K x M].  A: up to 4 bf16 segments, each [L_,512]
// row-major (segment = k>>9).  Wt: bf16 [M][K] (pre-transposed).  Epilogue:
// bias -> act -> colscale -> |*sscalep| -> *mulbuf(bf16) -> +addbuf(f32).
// Output: Of fp32 [.,M]  OR bf16 Ob0 (ld=M) OR split planes Ob0/Ob1 (ld=512).
__global__ __launch_bounds__(256)
void bgemm_k(const ushort* __restrict__ A0, const ushort* __restrict__ A1,
             const ushort* __restrict__ A2, const ushort* __restrict__ A3,
             const ushort* __restrict__ Wt, const float* __restrict__ bias,
             ushort* __restrict__ Ob0, ushort* __restrict__ Ob1, float* __restrict__ Of,
             int K, int M, int act,
             const float* __restrict__ colscale, const float* __restrict__ sscalep,
             const ushort* __restrict__ mulbuf, const float* __restrict__ addbuf)
{
    __shared__ ushort lA[128*32];
    __shared__ ushort lB[128*32];
    const ushort* Aseg[4] = {A0,A1,A2,A3};
    const int tid = threadIdx.x;
    const int lane = tid & 63, w = tid >> 6;
    const int wr = w >> 1, wc = w & 1;
    const int row0 = blockIdx.y * 128, col0 = blockIdx.x * 128;
    // staging: 512 chunks of 8 bf16; chunk c: row=c>>2, sub=c&3; thread t does c=t, c=t+256
    const int sr1 = tid >> 2, sc1 = tid & 3;
    const int sr2 = (tid + 256) >> 2;     // sub index identical (t+256)&3 == t&3

    f4 zero4 = {0.f,0.f,0.f,0.f};
    f4 acc[4][4];
    #pragma unroll
    for (int i=0;i<4;i++)
        #pragma unroll
        for (int j=0;j<4;j++) acc[i][j] = zero4;

    auto loadA = [&](int r, int sub, int kk)->bh8 {
        const ushort* p = Aseg[kk >> 9] + (size_t)(row0 + r) * 512 + (kk & 511) + sub*8;
        return *(const bh8*)p;
    };
    auto loadB = [&](int r, int sub, int kk)->bh8 {
        const ushort* p = Wt + (size_t)(col0 + r) * K + kk + sub*8;
        return *(const bh8*)p;
    };

    bh8 ra1 = loadA(sr1, sc1, 0), ra2 = loadA(sr2, sc1, 0);
    bh8 rb1 = loadB(sr1, sc1, 0), rb2 = loadB(sr2, sc1, 0);

    for (int kt = 0; kt < K; kt += 32) {
        __syncthreads();                       // LDS free (previous compute done)
        *(bh8*)&lA[sr1*32 + sc1*8] = ra1;
        *(bh8*)&lA[sr2*32 + sc1*8] = ra2;
        *(bh8*)&lB[sr1*32 + sc1*8] = rb1;
        *(bh8*)&lB[sr2*32 + sc1*8] = rb2;
        __syncthreads();
        if (kt + 32 < K) {                     // prefetch next K-step into regs
            ra1 = loadA(sr1, sc1, kt+32); ra2 = loadA(sr2, sc1, kt+32);
            rb1 = loadB(sr1, sc1, kt+32); rb2 = loadB(sr2, sc1, kt+32);
        }
        bh8 af[4], bfr[4];
        #pragma unroll
        for (int i=0;i<4;i++){
            af[i]  = *(const bh8*)&lA[(wr*64 + i*16 + (lane&15))*32 + (lane>>4)*8];
            bfr[i] = *(const bh8*)&lB[(wc*64 + i*16 + (lane&15))*32 + (lane>>4)*8];
        }
        #pragma unroll
        for (int i=0;i<4;i++)
            #pragma unroll
            for (int j=0;j<4;j++)
                acc[i][j] = __builtin_amdgcn_mfma_f32_16x16x32_bf16(af[i], bfr[j], acc[i][j], 0, 0, 0);
    }

    float ss = sscalep ? fabsf(*sscalep) : 1.0f;
    #pragma unroll
    for (int i=0;i<4;i++){
        int rr = row0 + wr*64 + i*16 + ((lane >> 4) << 2);
        #pragma unroll
        for (int j=0;j<4;j++){
            int cc = col0 + wc*64 + j*16 + (lane & 15);
            float bv = bias[cc];
            float cs = colscale ? fabsf(colscale[cc]) : 1.0f;
            #pragma unroll
            for (int q=0;q<4;q++){
                int r = rr + q;
                float t = acc[i][j][q] + bv;
                if (act==1) t = geluf(t);
                else if (act==2) t = 1.0f/(1.0f+expf(-t));
                else if (act==3) t = tanhf(t)*PI_F;
                t *= cs; t *= ss;
                if (mulbuf) t *= b2f(mulbuf[(size_t)r*M + cc]);
                if (addbuf) t += addbuf[(size_t)r*512 + cc];
                if (Of) Of[(size_t)r*M + cc] = t;
                else if (Ob1) {
                    if (cc < 512) Ob0[(size_t)r*512 + cc] = f2b(t);
                    else          Ob1[(size_t)r*512 + cc - 512] = f2b(t);
                } else Ob0[(size_t)r*M + cc] = f2b(t);
            }
        }
    }
}

// transpose W [K,M] fp32 -> Wt [M,K] bf16 (tiled)
__global__ __launch_bounds__(256)
void wtrans_k(const float* __restrict__ W, ushort* __restrict__ Wt, int K, int M)
{
    __shared__ float tile[32][33];
    int kb = blockIdx.y*32, mb = blockIdx.x*32;
    int tx = threadIdx.x & 31, ty = threadIdx.x >> 5;
    #pragma unroll
    for (int i = ty; i < 32; i += 8)
        tile[i][tx] = W[(size_t)(kb+i)*M + mb+tx];
    __syncthreads();
    #pragma unroll
    for (int i = ty; i < 32; i += 8)
        Wt[(size_t)(mb+i)*K + kb+tx] = f2b(tile[tx][i]);
}

// fp32 -> bf16 elementwise (x per batch)
__global__ __launch_bounds__(256)
void fconv_k(const float* __restrict__ in, ushort* __restrict__ out)
{
    size_t i = ((size_t)blockIdx.x*256 + threadIdx.x) * 4;
    float4 v = *(const float4*)(in + i);
    out[i+0]=f2b(v.x); out[i+1]=f2b(v.y); out[i+2]=f2b(v.z); out[i+3]=f2b(v.w);
}

// ---------------- scans ----------------
__global__ __launch_bounds__(256)
void s1a_k(const ushort* __restrict__ omega, const float* __restrict__ xb,
           float* __restrict__ csA, float* __restrict__ csX)
{
    int bid = blockIdx.x;                 // NC*2
    int dg = bid & 1, c = bid >> 1;
    int d = dg*256 + threadIdx.x;
    size_t base = (size_t)(c*CL)*D_ + d;
    float sA=0.f, sX=0.f;
    for (int l=0;l<CL;l++){
        sA += b2f(omega[base + (size_t)l*D_]);
        sX += xb[base + (size_t)l*D_];
    }
    size_t ci = (size_t)c*D_ + d;
    csA[ci]=sA; csX[ci]=sX;
}

__global__ void prefix_k(float* a, float* b2v, float* c3, int nbuf)
{
    int d = blockIdx.x*blockDim.x + threadIdx.x;
    if (d >= D_) return;
    float* bufs[3] = {a,b2v,c3};
    for (int i=0;i<nbuf;i++){
        float* p = bufs[i] + d;
        float run=0.f;
        for (int c=0;c<NC;c++){
            float v = p[(size_t)c*D_];
            p[(size_t)c*D_] = run;
            run += v;
        }
    }
}

// phi = phi_init + cumsum(omega) (fp32 stored); ctx = xcum/pos (bf16);
// chunk sums of magnitude, wv1*cos(phi), wv1*sin(phi)
__global__ __launch_bounds__(256)
void s1c_k(const ushort* __restrict__ omega, const float* __restrict__ xb,
           const ushort* __restrict__ phi_init,
           const ushort* __restrict__ magn, const ushort* __restrict__ wv1,
           const float* __restrict__ csA, const float* __restrict__ csX,
           float* __restrict__ phi, ushort* __restrict__ ctx,
           float* __restrict__ csM, float* __restrict__ csC, float* __restrict__ csS)
{
    int bid = blockIdx.x;
    int dg = bid & 1, c = bid >> 1;
    int d = dg*256 + threadIdx.x;
    size_t ci = (size_t)c*D_ + d;
    float phiacc = csA[ci], xacc = csX[ci];
    float sM=0.f,sC=0.f,sS=0.f;
    size_t base = (size_t)(c*CL)*D_ + d;
    for (int l=0;l<CL;l++){
        size_t idx = base + (size_t)l*D_;
        phiacc += b2f(omega[idx]);
        float ph = b2f(phi_init[idx]) + phiacc;
        phi[idx] = ph;
        float spv, cpv; sincosf(ph, &spv, &cpv);
        xacc += xb[idx];
        ctx[idx] = f2b(xacc / (float)(c*CL + l + 1));
        sM += b2f(magn[idx]);
        float wv = b2f(wv1[idx]);
        sC = fmaf(wv, cpv, sC); sS = fmaf(wv, spv, sS);
    }
    csM[ci]=sM; csC[ci]=sC; csS[ci]=sS;
}

// mem1 cumsums -> pos_ret (bf16)
__global__ __launch_bounds__(256)
void s1e_k(const ushort* __restrict__ magn, const ushort* __restrict__ wv1,
           const ushort* __restrict__ qoff, const float* __restrict__ phi,
           const float* __restrict__ csM, const float* __restrict__ csC,
           const float* __restrict__ csS, ushort* __restrict__ pos_ret)
{
    int bid = blockIdx.x;
    int dg = bid & 1, c = bid >> 1;
    int d = dg*256 + threadIdx.x;
    size_t ci = (size_t)c*D_ + d;
    float mA=csM[ci], cA=csC[ci], sA=csS[ci];
    size_t base = (size_t)(c*CL)*D_ + d;
    for (int l=0;l<CL;l++){
        size_t idx = base + (size_t)l*D_;
        mA += b2f(magn[idx]);
        float wv = b2f(wv1[idx]);
        float ph = phi[idx];
        float spv, cpv; sincosf(ph, &spv, &cpv);
        cA = fmaf(wv, cpv, cA); sA = fmaf(wv, spv, sA);
        float rs = rsqrtf(mA + 1e-8f);
        float sq, cq; sincosf(ph + b2f(qoff[idx]), &sq, &cq);
        pos_ret[idx] = f2b((cA*cq + sA*sq) * rs * 0.04419417382415922f); // 1/sqrt(512)
    }
}

// values (D->8) + store_gate (D->1)
__global__ __launch_bounds__(256)
void vencsg_k(const float* __restrict__ xb, const float* __restrict__ Wv,
              const float* __restrict__ bv, const float* __restrict__ Wg,
              const float* __restrict__ bg,
              float* __restrict__ vals, float* __restrict__ sgate)
{
    int gw = (int)((blockIdx.x*(size_t)blockDim.x + threadIdx.x) >> 6);
    int lane = threadIdx.x & 63;
    const float* xr = xb + (size_t)gw*D_;
    float pv[8] = {0,0,0,0,0,0,0,0}; float pg = 0.f;
    #pragma unroll
    for (int j=0;j<8;j++){
        int k = lane + 64*j;
        float xv = xr[k];
        #pragma unroll
        for (int v=0;v<8;v++) pv[v] = fmaf(xv, Wv[k*8+v], pv[v]);
        pg = fmaf(xv, Wg[k], pg);
    }
    #pragma unroll
    for (int off=32; off>0; off>>=1){
        #pragma unroll
        for (int v=0;v<8;v++) pv[v] += __shfl_down(pv[v], off, 64);
        pg += __shfl_down(pg, off, 64);
    }
    if (lane==0){
        #pragma unroll
        for (int v=0;v<8;v++) vals[(size_t)gw*8+v] = pv[v] + bv[v];
        sgate[gw] = 1.0f/(1.0f+expf(-(pg + bg[0])));
    }
}

// KV scan chunk sums
__global__ __launch_bounds__(256)
void s2a_k(const ushort* __restrict__ spb, const float* __restrict__ vals,
           const float* __restrict__ sgate,
           float* __restrict__ csKV, float* __restrict__ csG)
{
    int c = blockIdx.x;
    int t = threadIdx.x; int p = t & 127; int vb = (t>>7)*4;
    size_t nbase = (size_t)c*CL;
    float ac[4]={0,0,0,0}, as[4]={0,0,0,0}; float g=0.f;
    for (int l=0;l<CL;l++){
        size_t n = nbase + l;
        float sph = b2f(spb[n*(size_t)P_ + p]);
        float ssn, sc; sincosf(sph, &ssn, &sc);
        float sg = sgate[n];
        #pragma unroll
        for (int j=0;j<4;j++){
            float gv = vals[n*(size_t)V_ + vb + j] * sg;
            ac[j] = fmaf(sc, gv, ac[j]);
            as[j] = fmaf(ssn, gv, as[j]);
        }
        g += sg;
    }
    float* base = csKV + (size_t)c*2048;
    #pragma unroll
    for (int j=0;j<4;j++){
        base[p*V_ + vb + j] = ac[j];
        base[1024 + p*V_ + vb + j] = as[j];
    }
    if (t==0) csG[c] = g;
}

__global__ void s2b_k(float* csKV, float* csG)
{
    int t = blockIdx.x*blockDim.x + threadIdx.x;
    if (t < 2048){
        float* ptr = csKV + t;
        float run=0.f;
        for (int c=0;c<NC;c++){
            float v = ptr[(size_t)c*2048];
            ptr[(size_t)c*2048]=run;
            run+=v;
        }
    }
    if (t == 0){
        float run=0.f;
        for (int c=0;c<NC;c++){ float v=csG[c]; csG[c]=run; run+=v; }
    }
}

// KV replay + fused retrieval
__global__ __launch_bounds__(256)
void s2c_k(const ushort* __restrict__ spb, const float* __restrict__ vals,
           const float* __restrict__ sgate, const ushort* __restrict__ qp,
           const float* __restrict__ csKV, const float* __restrict__ csG,
           float* __restrict__ kvret)
{
    __shared__ float part[4][4];
    int c = blockIdx.x;
    int t = threadIdx.x; int p = t & 127; int vg = t >> 7; int vb = vg*4;
    int wave = t >> 6, lane = t & 63;
    size_t nbase = (size_t)c*CL;
    const float* kvb = csKV + (size_t)c*2048;
    float stc[4], sts[4];
    #pragma unroll
    for (int j=0;j<4;j++){ stc[j] = kvb[p*V_+vb+j]; sts[j] = kvb[1024 + p*V_+vb+j]; }
    float gacc = csG[c];
    for (int l=0;l<CL;l++){
        size_t n = nbase + l;
        float sph = b2f(spb[n*(size_t)P_ + p]);
        float ssn, sc; sincosf(sph, &ssn, &sc);
        float sg = sgate[n]; gacc += sg;
        #pragma unroll
        for (int j=0;j<4;j++){
            float gv = vals[n*(size_t)V_ + vb + j]*sg;
            stc[j] = fmaf(sc, gv, stc[j]);
            sts[j] = fmaf(ssn, gv, sts[j]);
        }
        float qph = b2f(qp[n*(size_t)P_ + p]);
        float qs, qc; sincosf(qph, &qs, &qc);
        float r[4];
        #pragma unroll
        for (int j=0;j<4;j++) r[j] = qc*stc[j] + qs*sts[j];
        #pragma unroll
        for (int off=1; off<64; off<<=1){
            #pragma unroll
            for (int j=0;j<4;j++) r[j] += __shfl_xor(r[j], off, 64);
        }
        if (lane==0){
            part[wave][0]=r[0]; part[wave][1]=r[1]; part[wave][2]=r[2]; part[wave][3]=r[3];
        }
        __syncthreads();
        if (t < 8){
            int v = t, vgg = v>>2, jj = v&3;
            float s = part[vgg*2][jj] + part[vgg*2+1][jj];
            float gc = fmaxf(gacc, 1.0f);
            kvret[n*(size_t)V_ + v] = s * rsqrtf(gc) * 0.08838834764831845f; // 1/sqrt(128)
        }
        __syncthreads();
    }
}

// kv_out = kvret @ W_kvo + b  -> bf16
__global__ __launch_bounds__(256)
void kvo_k(const float* __restrict__ kvret, const float* __restrict__ Wkvo,
           const float* __restrict__ bkvo, ushort* __restrict__ kvout)
{
    size_t idx = (size_t)blockIdx.x*256 + threadIdx.x;
    size_t n = idx >> 9; int d = (int)(idx & 511);
    float s = bkvo[d];
    #pragma unroll
    for (int v=0;v<8;v++) s = fmaf(kvret[n*8+v], Wkvo[v*512 + d], s);
    kvout[idx] = f2b(s);
}

// combined + LayerNorm -> 4 bf16 planes
__global__ __launch_bounds__(256)
void cmb_k(const ushort* __restrict__ pos_out, const ushort* __restrict__ kv_out,
           const float* __restrict__ xb, const float* __restrict__ phi,
           const float* __restrict__ ln_g, const float* __restrict__ ln_b,
           ushort* __restrict__ p0, ushort* __restrict__ p1,
           ushort* __restrict__ p2, ushort* __restrict__ p3)
{
    __shared__ float red[8];
    int n = blockIdx.x; int t = threadIdx.x;
    int wave = t>>6, lane = t&63;
    float v_[8]; float sum=0.f, sumsq=0.f;
    #pragma unroll
    for (int i=0;i<8;i++){
        int cidx = t + i*256;
        int seg = cidx >> 9, cc = cidx & 511;
        size_t id = (size_t)n*D_ + cc;
        float v;
        if (seg==0) v = b2f(pos_out[id]);
        else if (seg==1) v = b2f(kv_out[id]);
        else {
            float sp, cp; sincosf(phi[id], &sp, &cp);
            v = xb[id] * ((seg==2) ? cp : sp);
        }
        v_[i]=v; sum += v; sumsq = fmaf(v,v,sumsq);
    }
    #pragma unroll
    for (int off=32; off>0; off>>=1){
        sum += __shfl_xor(sum, off, 64);
        sumsq += __shfl_xor(sumsq, off, 64);
    }
    if (lane==0){ red[wave]=sum; red[wave+4]=sumsq; }
    __syncthreads();
    float s = red[0]+red[1]+red[2]+red[3];
    float q = red[4]+red[5]+red[6]+red[7];
    float mu = s * (1.0f/2048.0f);
    float var = q * (1.0f/2048.0f) - mu*mu;
    float rstd = rsqrtf(var + 1e-5f);
    #pragma unroll
    for (int i=0;i<8;i++){
        int cidx = t + i*256;
        int seg = cidx >> 9, cc = cidx & 511;
        float h = (v_[i]-mu)*rstd*ln_g[cidx] + ln_b[cidx];
        ushort* pp = (seg==0)?p0:(seg==1)?p1:(seg==2)?p2:p3;
        pp[(size_t)n*D_ + cc] = f2b(h);
    }
}

// diagnostic fallback
__global__ void copyx_k(const float* __restrict__ x, float* __restrict__ out, size_t n)
{
    size_t i = (size_t)blockIdx.x*256 + threadIdx.x;
    if (i < n) out[i] = x[i];
}

extern "C" void kernel_launch(void* const* d_in, const int* in_sizes, int n_in,
                              void* d_out, int out_size, void* d_ws, size_t ws_size,
                              hipStream_t stream)
{
    const float* x        =(const float*)d_in[0];
    const float* W_omega  =(const float*)d_in[1];  const float* b_omega=(const float*)d_in[2];
    const float* omega_sc =(const float*)d_in[3];
    const float* W_pi1    =(const float*)d_in[4];  const float* b_pi1 =(const float*)d_in[5];
    const float* W_pi2    =(const float*)d_in[6];  const float* b_pi2 =(const float*)d_in[7];
    const float* W_m1v    =(const float*)d_in[8];  const float* b_m1v =(const float*)d_in[9];
    const float* W_m1o    =(const float*)d_in[10]; const float* b_m1o =(const float*)d_in[11];
    const float* W_mag    =(const float*)d_in[12]; const float* b_mag =(const float*)d_in[13];
    const float* mag_sc   =(const float*)d_in[14];
    const float* W_qoff   =(const float*)d_in[15]; const float* b_qoff=(const float*)d_in[16];
    const float* W_kenc   =(const float*)d_in[17]; const float* b_kenc=(const float*)d_in[18];
    const float* W_venc   =(const float*)d_in[19]; const float* b_venc=(const float*)d_in[20];
    const float* W_sk1    =(const float*)d_in[21]; const float* b_sk1 =(const float*)d_in[22];
    const float* W_sk2    =(const float*)d_in[23]; const float* b_sk2 =(const float*)d_in[24];
    const float* W_sg     =(const float*)d_in[25]; const float* b_sg  =(const float*)d_in[26];
    const float* W_kvo    =(const float*)d_in[27]; const float* b_kvo =(const float*)d_in[28];
    const float* ln_g     =(const float*)d_in[29]; const float* ln_b  =(const float*)d_in[30];
    const float* W_o1     =(const float*)d_in[31]; const float* b_o1  =(const float*)d_in[32];
    const float* W_o2     =(const float*)d_in[33]; const float* b_o2  =(const float*)d_in[34];
    float* out = (float*)d_out;

    char* wsb = (char*)d_ws;
    size_t off = 0;
    auto allocB = [&](size_t bytes)->void* {
        void* p = wsb + off; off = (off + bytes + 255) & ~(size_t)255; return p;
    };
    // bf16 weight transposes [M][K] — once per launch
    ushort* wt_omega=(ushort*)allocB(512*512*2);
    ushort* wt_mag  =(ushort*)allocB(512*512*2);
    ushort* wt_m1v  =(ushort*)allocB(512*512*2);
    ushort* wt_pi1  =(ushort*)allocB(512*512*2);
    ushort* wt_pi2  =(ushort*)allocB(512*512*2);
    ushort* wt_qoff =(ushort*)allocB(512*512*2);
    ushort* wt_m1o  =(ushort*)allocB(512*512*2);
    ushort* wt_kenc =(ushort*)allocB(128*512*2);
    ushort* wt_sk1  =(ushort*)allocB(512*1024*2);
    ushort* wt_sk2  =(ushort*)allocB(128*512*2);
    ushort* wt_o1   =(ushort*)allocB(1024*2048*2);
    ushort* wt_o2   =(ushort*)allocB(512*1024*2);
    // per-batch bf16 slots [L_,512]
    ushort* xbf =(ushort*)allocB(LD*2);
    ushort* b0  =(ushort*)allocB(LD*2);  // omega -> plane0
    ushort* b1  =(ushort*)allocB(LD*2);  // magnitude -> plane1
    ushort* b2s =(ushort*)allocB(LD*2);  // wv1 -> plane2
    ushort* b3  =(ushort*)allocB(LD*2);  // pi1g -> ctx -> plane3
    ushort* b4  =(ushort*)allocB(LD*2);  // phi_init -> pos_ret -> h1a
    ushort* b5  =(ushort*)allocB(LD*2);  // qoff -> sk1g -> h1b
    ushort* b6  =(ushort*)allocB(LD*2);  // pos_out
    ushort* b7  =(ushort*)allocB(LD*2);  // kv_out
    float*  phi =(float*)allocB(LD*4);   // fp32 phi
    ushort* qp  =(ushort*)allocB((size_t)L_*P_*2);
    ushort* spb =(ushort*)allocB((size_t)L_*P_*2);
    float* vals =(float*)allocB((size_t)L_*V_*4);
    float* sgate=(float*)allocB((size_t)L_*4);
    float* kvret=(float*)allocB((size_t)L_*V_*4);
    float* csA =(float*)allocB((size_t)NC*D_*4);
    float* csX =(float*)allocB((size_t)NC*D_*4);
    float* csM =(float*)allocB((size_t)NC*D_*4);
    float* csC =(float*)allocB((size_t)NC*D_*4);
    float* csS =(float*)allocB((size_t)NC*D_*4);
    float* csKV=(float*)allocB((size_t)NC*2048*4);
    float* csG =(float*)allocB(NC*4);
    if (off > ws_size) {
        copyx_k<<<dim3((unsigned)(((size_t)N_*D_ + 255)/256)), dim3(256), 0, stream>>>(x, out, (size_t)N_*D_);
        return;
    }

    dim3 blk(256);
    auto wt = [&](const float* W, ushort* Wt, int K, int M){
        wtrans_k<<<dim3(M/32, K/32), blk, 0, stream>>>(W, Wt, K, M);
    };
    wt(W_omega,wt_omega,512,512); wt(W_mag,wt_mag,512,512); wt(W_m1v,wt_m1v,512,512);
    wt(W_pi1,wt_pi1,512,512);     wt(W_pi2,wt_pi2,512,512); wt(W_qoff,wt_qoff,512,512);
    wt(W_m1o,wt_m1o,512,512);     wt(W_kenc,wt_kenc,512,128);
    wt(W_sk1,wt_sk1,1024,512);    wt(W_sk2,wt_sk2,512,128);
    wt(W_o1,wt_o1,2048,1024);     wt(W_o2,wt_o2,1024,512);

    auto gemm = [&](const ushort* A0,const ushort* A1,const ushort* A2,const ushort* A3,
                    const ushort* Wt,const float* bias,
                    ushort* Ob0, ushort* Ob1, float* Of, int K,int M,int act,
                    const float* colscale,const float* sscale,const ushort* mul,const float* add){
        dim3 grid(M/128, L_/128);
        bgemm_k<<<grid, blk, 0, stream>>>(A0,A1,A2,A3,Wt,bias,Ob0,Ob1,Of,K,M,act,colscale,sscale,mul,add);
    };

    for (int b = 0; b < B_; ++b) {
        const float* xb = x + (size_t)b*LD;
        float* outb = out + (size_t)b*LD;

        fconv_k<<<dim3((unsigned)(LD/1024)), blk, 0, stream>>>(xb, xbf);

        gemm(xbf,0,0,0, wt_omega,b_omega, b0,0,0, 512,512,0, omega_sc,0,0,0);   // omega_scaled
        gemm(xbf,0,0,0, wt_mag,  b_mag,   b1,0,0, 512,512,2, 0,mag_sc,0,0);     // magnitude
        gemm(xbf,0,0,0, wt_m1v,  b_m1v,   b2s,0,0,512,512,0, 0,0,b1,0);         // wv1
        gemm(xbf,0,0,0, wt_pi1,  b_pi1,   b3,0,0, 512,512,1, 0,0,0,0);          // gelu(x@W_pi1)
        gemm(b3,0,0,0,  wt_pi2,  b_pi2,   b4,0,0, 512,512,0, 0,0,0,0);          // phi_init
        gemm(xbf,0,0,0, wt_qoff, b_qoff,  b5,0,0, 512,512,0, 0,0,0,0);          // qoff
        gemm(xbf,0,0,0, wt_kenc, b_kenc,  qp,0,0, 512,128,3, 0,0,0,0);          // query_phase
        vencsg_k<<<dim3((L_*64)/256), blk, 0, stream>>>(xb, W_venc,b_venc, W_sg,b_sg, vals, sgate);

        s1a_k<<<dim3(NC*2), blk, 0, stream>>>(b0, xb, csA, csX);
        prefix_k<<<dim3(2), blk, 0, stream>>>(csA, csX, (float*)0, 2);
        s1c_k<<<dim3(NC*2), blk, 0, stream>>>(b0, xb, b4, b1, b2s, csA, csX, phi, b3, csM, csC, csS);
        prefix_k<<<dim3(2), blk, 0, stream>>>(csM, csC, csS, 3);
        s1e_k<<<dim3(NC*2), blk, 0, stream>>>(b1, b2s, b5, phi, csM, csC, csS, b4); // b4 = pos_ret

        gemm(b4,0,0,0, wt_m1o,b_m1o, b6,0,0, 512,512,0, 0,0,0,0);               // pos_out
        gemm(xbf,b3,0,0, wt_sk1,b_sk1, b5,0,0, 1024,512,1, 0,0,0,0);            // sk1g
        gemm(b5,0,0,0, wt_sk2,b_sk2, spb,0,0, 512,128,3, 0,0,0,0);              // storage_phase

        s2a_k<<<dim3(NC), blk, 0, stream>>>(spb, vals, sgate, csKV, csG);
        s2b_k<<<dim3(8), blk, 0, stream>>>(csKV, csG);
        s2c_k<<<dim3(NC), blk, 0, stream>>>(spb, vals, sgate, qp, csKV, csG, kvret);
        kvo_k<<<dim3((unsigned)(LD/256)), blk, 0, stream>>>(kvret, W_kvo, b_kvo, b7); // kv_out

        cmb_k<<<dim3(L_), blk, 0, stream>>>(b6, b7, xb, phi, ln_g, ln_b, b0, b1, b2s, b3);
        gemm(b0,b1,b2s,b3, wt_o1,b_o1, b4,b5,0, 2048,1024,1, 0,0,0,0);          // h1 -> b4,b5
        gemm(b4,b5,0,0,    wt_o2,b_o2, 0,0,outb, 1024,512,0, 0,0,0,xb);         // out = x + ...
    }
}

// Round 4
// 2344.355 us; speedup vs baseline: 1.7019x; 1.0350x over previous
//
#include <hip/hip_runtime.h>
#include <math.h>

#define B_ 4
#define L_ 4096
#define D_ 512
#define P_ 128
#define V_ 8
#define N_ (B_*L_)
#define NC 64               // chunks per batch for s1 scans
#define CL (L_/NC)          // 64 positions per chunk
#define LD ((size_t)L_*D_)  // per-batch plane elems
#define PI_F 3.14159265358979323846f

typedef unsigned short ushort;
typedef __attribute__((ext_vector_type(8))) short bh8;   // 8 bf16 in 4 VGPRs
typedef __attribute__((ext_vector_type(4))) float f4;

__device__ __forceinline__ float geluf(float v){
    return 0.5f*v*(1.0f+erff(v*0.7071067811865475f));
}
__device__ __forceinline__ ushort f2b(float f){
    union { float f; unsigned u; } v; v.f = f;
    unsigned r = (v.u + 0x7fffu + ((v.u >> 16) & 1u)) >> 16;
    return (ushort)r;
}
__device__ __forceinline__ float b2f(ushort h){
    union { unsigned u; float f; } v; v.u = ((unsigned)h) << 16;
    return v.f;
}

// ---------------- bf16 MFMA GEMM ----------------
// C[R x M] = A[R x K] @ W[K x M].  A: up to 4 bf16 segments, each [R,512]
// row-major (segment = k>>9).  Wt: bf16 [M][K].  Epilogue:
// bias -> act -> colscale -> |*sscalep| -> *mulbuf(bf16) -> +addbuf(f32).
// act==4: ph = tanh(t)*pi; Ob0=cos(ph), Ob1=sin(ph) (both ld=M).
// Output: Of fp32 (ld=M) OR bf16 Ob0 (ld=M) OR split planes Ob0/Ob1 (ld=512).
__global__ __launch_bounds__(256)
void bgemm_k(const ushort* __restrict__ A0, const ushort* __restrict__ A1,
             const ushort* __restrict__ A2, const ushort* __restrict__ A3,
             const ushort* __restrict__ Wt, const float* __restrict__ bias,
             ushort* __restrict__ Ob0, ushort* __restrict__ Ob1, float* __restrict__ Of,
             int K, int M, int act,
             const float* __restrict__ colscale, const float* __restrict__ sscalep,
             const ushort* __restrict__ mulbuf, const float* __restrict__ addbuf)
{
    __shared__ ushort lA[128*32];
    __shared__ ushort lB[128*32];
    const ushort* Aseg[4] = {A0,A1,A2,A3};
    const int tid = threadIdx.x;
    const int lane = tid & 63, w = tid >> 6;
    const int wr = w >> 1, wc = w & 1;
    const int row0 = blockIdx.y * 128, col0 = blockIdx.x * 128;
    const int sr1 = tid >> 2, sc1 = tid & 3;
    const int sr2 = (tid + 256) >> 2;

    f4 zero4 = {0.f,0.f,0.f,0.f};
    f4 acc[4][4];
    #pragma unroll
    for (int i=0;i<4;i++)
        #pragma unroll
        for (int j=0;j<4;j++) acc[i][j] = zero4;

    auto loadA = [&](int r, int sub, int kk)->bh8 {
        const ushort* p = Aseg[kk >> 9] + (size_t)(row0 + r) * 512 + (kk & 511) + sub*8;
        return *(const bh8*)p;
    };
    auto loadB = [&](int r, int sub, int kk)->bh8 {
        const ushort* p = Wt + (size_t)(col0 + r) * K + kk + sub*8;
        return *(const bh8*)p;
    };

    bh8 ra1 = loadA(sr1, sc1, 0), ra2 = loadA(sr2, sc1, 0);
    bh8 rb1 = loadB(sr1, sc1, 0), rb2 = loadB(sr2, sc1, 0);

    for (int kt = 0; kt < K; kt += 32) {
        __syncthreads();
        *(bh8*)&lA[sr1*32 + sc1*8] = ra1;
        *(bh8*)&lA[sr2*32 + sc1*8] = ra2;
        *(bh8*)&lB[sr1*32 + sc1*8] = rb1;
        *(bh8*)&lB[sr2*32 + sc1*8] = rb2;
        __syncthreads();
        if (kt + 32 < K) {
            ra1 = loadA(sr1, sc1, kt+32); ra2 = loadA(sr2, sc1, kt+32);
            rb1 = loadB(sr1, sc1, kt+32); rb2 = loadB(sr2, sc1, kt+32);
        }
        bh8 af[4], bfr[4];
        #pragma unroll
        for (int i=0;i<4;i++){
            af[i]  = *(const bh8*)&lA[(wr*64 + i*16 + (lane&15))*32 + (lane>>4)*8];
            bfr[i] = *(const bh8*)&lB[(wc*64 + i*16 + (lane&15))*32 + (lane>>4)*8];
        }
        #pragma unroll
        for (int i=0;i<4;i++)
            #pragma unroll
            for (int j=0;j<4;j++)
                acc[i][j] = __builtin_amdgcn_mfma_f32_16x16x32_bf16(af[i], bfr[j], acc[i][j], 0, 0, 0);
    }

    float ss = sscalep ? fabsf(*sscalep) : 1.0f;
    #pragma unroll
    for (int i=0;i<4;i++){
        int rr = row0 + wr*64 + i*16 + ((lane >> 4) << 2);
        #pragma unroll
        for (int j=0;j<4;j++){
            int cc = col0 + wc*64 + j*16 + (lane & 15);
            float bv = bias[cc];
            float cs = colscale ? fabsf(colscale[cc]) : 1.0f;
            #pragma unroll
            for (int q=0;q<4;q++){
                int r = rr + q;
                float t = acc[i][j][q] + bv;
                if (act==4){
                    float sv, cv; sincosf(tanhf(t)*PI_F, &sv, &cv);
                    Ob0[(size_t)r*M + cc] = f2b(cv);
                    Ob1[(size_t)r*M + cc] = f2b(sv);
                    continue;
                }
                if (act==1) t = geluf(t);
                else if (act==2) t = 1.0f/(1.0f+expf(-t));
                else if (act==3) t = tanhf(t)*PI_F;
                t *= cs; t *= ss;
                if (mulbuf) t *= b2f(mulbuf[(size_t)r*M + cc]);
                if (addbuf) t += addbuf[(size_t)r*512 + cc];
                if (Of) Of[(size_t)r*M + cc] = t;
                else if (Ob1) {
                    if (cc < 512) Ob0[(size_t)r*512 + cc] = f2b(t);
                    else          Ob1[(size_t)r*512 + cc - 512] = f2b(t);
                } else Ob0[(size_t)r*M + cc] = f2b(t);
            }
        }
    }
}

// transpose W [K,M] fp32 -> Wt [M,K] bf16
__global__ __launch_bounds__(256)
void wtrans_k(const float* __restrict__ W, ushort* __restrict__ Wt, int K, int M)
{
    __shared__ float tile[32][33];
    int kb = blockIdx.y*32, mb = blockIdx.x*32;
    int tx = threadIdx.x & 31, ty = threadIdx.x >> 5;
    #pragma unroll
    for (int i = ty; i < 32; i += 8)
        tile[i][tx] = W[(size_t)(kb+i)*M + mb+tx];
    __syncthreads();
    #pragma unroll
    for (int i = ty; i < 32; i += 8)
        Wt[(size_t)(mb+i)*K + kb+tx] = f2b(tile[tx][i]);
}

// fp32 -> bf16 elementwise
__global__ __launch_bounds__(256)
void fconv_k(const float* __restrict__ in, ushort* __restrict__ out)
{
    size_t i = ((size_t)blockIdx.x*256 + threadIdx.x) * 4;
    float4 v = *(const float4*)(in + i);
    out[i+0]=f2b(v.x); out[i+1]=f2b(v.y); out[i+2]=f2b(v.z); out[i+3]=f2b(v.w);
}

// ---------------- s1 scans (batch-aware) ----------------
__global__ __launch_bounds__(256)
void s1a_k(const ushort* __restrict__ omega, const float* __restrict__ xg,
           float* __restrict__ csA, float* __restrict__ csX)
{
    int bid = blockIdx.x;                 // NB*NC*2
    int b = bid >> 7; int rem = bid & 127;
    int dg = rem & 1, c = rem >> 1;
    int d = dg*256 + threadIdx.x;
    size_t base = ((size_t)b*L_ + (size_t)c*CL)*D_ + d;
    float sA=0.f, sX=0.f;
    for (int l=0;l<CL;l++){
        sA += b2f(omega[base + (size_t)l*D_]);
        sX += xg[base + (size_t)l*D_];
    }
    size_t ci = ((size_t)b*NC + c)*D_ + d;
    csA[ci]=sA; csX[ci]=sX;
}

// exclusive prefix over chunk dim; threads = NB*D_
__global__ void prefix_k(float* a, float* b2v, float* c3, int nbuf)
{
    int t = blockIdx.x*blockDim.x + threadIdx.x;
    int b = t >> 9, d = t & 511;
    float* bufs[3] = {a,b2v,c3};
    for (int i=0;i<nbuf;i++){
        float* p = bufs[i] + ((size_t)b*NC)*D_ + d;
        float run=0.f;
        for (int c=0;c<NC;c++){
            float v = p[(size_t)c*D_];
            p[(size_t)c*D_] = run;
            run += v;
        }
    }
}

__global__ __launch_bounds__(256)
void s1c_k(const ushort* __restrict__ omega, const float* __restrict__ xg,
           const ushort* __restrict__ phi_init,
           const ushort* __restrict__ magn, const ushort* __restrict__ wv1,
           const float* __restrict__ csA, const float* __restrict__ csX,
           float* __restrict__ phi, ushort* __restrict__ ctx,
           float* __restrict__ csM, float* __restrict__ csC, float* __restrict__ csS)
{
    int bid = blockIdx.x;
    int b = bid >> 7; int rem = bid & 127;
    int dg = rem & 1, c = rem >> 1;
    int d = dg*256 + threadIdx.x;
    size_t ci = ((size_t)b*NC + c)*D_ + d;
    float phiacc = csA[ci], xacc = csX[ci];
    float sM=0.f,sC=0.f,sS=0.f;
    size_t base = ((size_t)b*L_ + (size_t)c*CL)*D_ + d;
    for (int l=0;l<CL;l++){
        size_t idx = base + (size_t)l*D_;
        phiacc += b2f(omega[idx]);
        float ph = b2f(phi_init[idx]) + phiacc;
        phi[idx] = ph;
        float spv, cpv; sincosf(ph, &spv, &cpv);
        xacc += xg[idx];
        ctx[idx] = f2b(xacc / (float)(c*CL + l + 1));
        sM += b2f(magn[idx]);
        float wv = b2f(wv1[idx]);
        sC = fmaf(wv, cpv, sC); sS = fmaf(wv, spv, sS);
    }
    csM[ci]=sM; csC[ci]=sC; csS[ci]=sS;
}

__global__ __launch_bounds__(256)
void s1e_k(const ushort* __restrict__ magn, const ushort* __restrict__ wv1,
           const ushort* __restrict__ qoff, const float* __restrict__ phi,
           const float* __restrict__ csM, const float* __restrict__ csC,
           const float* __restrict__ csS, ushort* __restrict__ pos_ret)
{
    int bid = blockIdx.x;
    int b = bid >> 7; int rem = bid & 127;
    int dg = rem & 1, c = rem >> 1;
    int d = dg*256 + threadIdx.x;
    size_t ci = ((size_t)b*NC + c)*D_ + d;
    float mA=csM[ci], cA=csC[ci], sA=csS[ci];
    size_t base = ((size_t)b*L_ + (size_t)c*CL)*D_ + d;
    for (int l=0;l<CL;l++){
        size_t idx = base + (size_t)l*D_;
        mA += b2f(magn[idx]);
        float wv = b2f(wv1[idx]);
        float ph = phi[idx];
        float spv, cpv; sincosf(ph, &spv, &cpv);
        cA = fmaf(wv, cpv, cA); sA = fmaf(wv, spv, sA);
        float rs = rsqrtf(mA + 1e-8f);
        float sq, cq; sincosf(ph + b2f(qoff[idx]), &sq, &cq);
        pos_ret[idx] = f2b((cA*cq + sA*sq) * rs * 0.04419417382415922f); // 1/sqrt(512)
    }
}

// values (D->8)*gate -> gvb (bf16), store_gate -> sgate
__global__ __launch_bounds__(256)
void vencsg_k(const float* __restrict__ xg, const float* __restrict__ Wv,
              const float* __restrict__ bv, const float* __restrict__ Wg,
              const float* __restrict__ bg,
              ushort* __restrict__ gvb, float* __restrict__ sgate)
{
    int gw = (int)((blockIdx.x*(size_t)blockDim.x + threadIdx.x) >> 6);
    int lane = threadIdx.x & 63;
    const float* xr = xg + (size_t)gw*D_;
    float pv[8] = {0,0,0,0,0,0,0,0}; float pg = 0.f;
    #pragma unroll
    for (int j=0;j<8;j++){
        int k = lane + 64*j;
        float xv = xr[k];
        #pragma unroll
        for (int v=0;v<8;v++) pv[v] = fmaf(xv, Wv[k*8+v], pv[v]);
        pg = fmaf(xv, Wg[k], pg);
    }
    #pragma unroll
    for (int off=32; off>0; off>>=1){
        #pragma unroll
        for (int v=0;v<8;v++) pv[v] += __shfl_down(pv[v], off, 64);
        pg += __shfl_down(pg, off, 64);
    }
    if (lane==0){
        float sg = 1.0f/(1.0f+expf(-(pg + bg[0])));
        #pragma unroll
        for (int v=0;v<8;v++) gvb[(size_t)gw*8+v] = f2b((pv[v] + bv[v]) * sg);
        sgate[gw] = sg;
    }
}

// inclusive cumsum of sgate -> rinv = rsqrt(max(cum,1)); one block per batch
__global__ __launch_bounds__(256)
void gatescan_k(const float* __restrict__ sgate, float* __restrict__ rinv)
{
    __shared__ float wsum[4];
    __shared__ float carry;
    int b = blockIdx.x; int t = threadIdx.x;
    int lane = t & 63, wave = t >> 6;
    if (t == 0) carry = 0.f;
    __syncthreads();
    for (int s = 0; s < L_/256; s++){
        float v = sgate[(size_t)b*L_ + s*256 + t];
        float sc = v;
        #pragma unroll
        for (int off=1; off<64; off<<=1){
            float u = __shfl_up(sc, off, 64);
            if (lane >= off) sc += u;
        }
        if (lane == 63) wsum[wave] = sc;
        __syncthreads();
        float woff = carry;
        for (int w2 = 0; w2 < wave; w2++) woff += wsum[w2];
        float inc = sc + woff;
        rinv[(size_t)b*L_ + s*256 + t] = rsqrtf(fmaxf(inc, 1.0f));
        __syncthreads();
        if (t == 255) carry = inc;
        __syncthreads();
    }
}

// KV chunk sums (chunk=64): state[p][v] cos/sin contributions
__global__ __launch_bounds__(256)
void kvsum_k(const ushort* __restrict__ Kc, const ushort* __restrict__ Ks,
             const ushort* __restrict__ gvb, float* __restrict__ csKV)
{
    int bid = blockIdx.x;            // NB*64
    int b = bid >> 6, c = bid & 63;
    int t = threadIdx.x; int p = t & 127; int v0 = (t>>7)*4;
    size_t row0 = (size_t)b*L_ + (size_t)c*64;
    float ac[4]={0,0,0,0}, as[4]={0,0,0,0};
    for (int l=0;l<64;l++){
        size_t r = row0 + l;
        float kc = b2f(Kc[r*(size_t)P_ + p]);
        float ks = b2f(Ks[r*(size_t)P_ + p]);
        #pragma unroll
        for (int j=0;j<4;j++){
            float gv = b2f(gvb[r*(size_t)V_ + v0 + j]);
            ac[j] = fmaf(kc, gv, ac[j]);
            as[j] = fmaf(ks, gv, as[j]);
        }
    }
    float* base = csKV + ((size_t)b*64 + c)*2048;
    #pragma unroll
    for (int j=0;j<4;j++){
        base[p*V_ + v0 + j] = ac[j];
        base[1024 + p*V_ + v0 + j] = as[j];
    }
}

// exclusive prefix of state over 64 chunks; threads = NB*2048
__global__ void kvpfx_k(float* __restrict__ csKV)
{
    int t = blockIdx.x*blockDim.x + threadIdx.x;
    int b = t >> 11, si = t & 2047;
    float* ptr = csKV + ((size_t)b*64)*2048 + si;
    float run=0.f;
    for (int c=0;c<64;c++){
        float v = ptr[(size_t)c*2048];
        ptr[(size_t)c*2048] = run;
        run += v;
    }
}

// per-64-row-tile: checkpoint retrieval + causal diagonal via MFMA
__global__ __launch_bounds__(256)
void kv2_k(const ushort* __restrict__ Qc, const ushort* __restrict__ Qs,
           const ushort* __restrict__ Kc, const ushort* __restrict__ Ks,
           const ushort* __restrict__ gvb, const float* __restrict__ rinv,
           const float* __restrict__ csKV, float* __restrict__ kvret)
{
    __shared__ ushort sS[64][66];
    __shared__ float sM[2048];       // Mc[p*8+v] then Ms
    __shared__ float sgv[64][8];
    int tile = blockIdx.x, b = blockIdx.y;
    int t = threadIdx.x, lane = t & 63, w = t >> 6;
    int wr = w >> 1, wc = w & 1;
    size_t row0 = (size_t)b*L_ + (size_t)tile*64;
    const float* kvb = csKV + ((size_t)b*64 + tile)*2048;
    #pragma unroll
    for (int k=0;k<8;k++) sM[t + k*256] = kvb[t + k*256];
    #pragma unroll
    for (int k=0;k<2;k++){
        int idx = t + k*256; int l = idx >> 3, v = idx & 7;
        sgv[l][v] = b2f(gvb[(row0 + l)*(size_t)V_ + v]);
    }
    // stage 1: S = Qc Kc^T + Qs Ks^T (64x64), 4 waves each 32x32
    f4 zero4 = {0.f,0.f,0.f,0.f};
    f4 acc[2][2];
    #pragma unroll
    for (int i=0;i<2;i++)
        #pragma unroll
        for (int j=0;j<2;j++) acc[i][j] = zero4;
    #pragma unroll
    for (int ks=0; ks<8; ks++){
        const ushort* Ab = (ks<4) ? Qc : Qs;
        const ushort* Bb = (ks<4) ? Kc : Ks;
        int kb = (ks&3)*32 + (lane>>4)*8;
        bh8 af[2], bfr[2];
        #pragma unroll
        for (int i=0;i<2;i++)
            af[i] = *(const bh8*)(Ab + (row0 + wr*32 + i*16 + (lane&15))*(size_t)P_ + kb);
        #pragma unroll
        for (int j=0;j<2;j++)
            bfr[j] = *(const bh8*)(Bb + (row0 + wc*32 + j*16 + (lane&15))*(size_t)P_ + kb);
        #pragma unroll
        for (int i=0;i<2;i++)
            #pragma unroll
            for (int j=0;j<2;j++)
                acc[i][j] = __builtin_amdgcn_mfma_f32_16x16x32_bf16(af[i], bfr[j], acc[i][j], 0, 0, 0);
    }
    #pragma unroll
    for (int i=0;i<2;i++){
        #pragma unroll
        for (int j=0;j<2;j++){
            int cc = wc*32 + j*16 + (lane & 15);
            #pragma unroll
            for (int q=0;q<4;q++){
                int lr = wr*32 + i*16 + ((lane>>4)<<2) + q;
                sS[lr][cc] = f2b((cc <= lr) ? acc[i][j][q] : 0.f);
            }
        }
    }
    __syncthreads();
    // stage 2: per (row, v-pair) dot with checkpoint + S@gv
    int l = t & 63, vh = t >> 6; int v0 = vh*2;
    const ushort* qcr = Qc + (row0 + l)*(size_t)P_;
    const ushort* qsr = Qs + (row0 + l)*(size_t)P_;
    float a0=0.f, a1=0.f;
    #pragma unroll
    for (int pc=0; pc<16; pc++){
        bh8 qc8 = *(const bh8*)(qcr + pc*8);
        bh8 qs8 = *(const bh8*)(qsr + pc*8);
        #pragma unroll
        for (int e=0;e<8;e++){
            int p = pc*8+e;
            float qc = b2f((ushort)qc8[e]), qs = b2f((ushort)qs8[e]);
            a0 += qc*sM[p*8+v0]   + qs*sM[1024+p*8+v0];
            a1 += qc*sM[p*8+v0+1] + qs*sM[1024+p*8+v0+1];
        }
    }
    for (int c=0;c<64;c++){
        float sv = b2f(sS[l][c]);
        a0 = fmaf(sv, sgv[c][v0],   a0);
        a1 = fmaf(sv, sgv[c][v0+1], a1);
    }
    float rn = rinv[row0 + l] * 0.08838834764831845f; // 1/sqrt(128)
    kvret[(row0+l)*(size_t)V_ + v0]   = a0*rn;
    kvret[(row0+l)*(size_t)V_ + v0+1] = a1*rn;
}

// kv_out = kvret @ W_kvo + b  -> bf16
__global__ __launch_bounds__(256)
void kvo_k(const float* __restrict__ kvret, const float* __restrict__ Wkvo,
           const float* __restrict__ bkvo, ushort* __restrict__ kvout)
{
    size_t idx = (size_t)blockIdx.x*256 + threadIdx.x;
    size_t n = idx >> 9; int d = (int)(idx & 511);
    float s = bkvo[d];
    #pragma unroll
    for (int v=0;v<8;v++) s = fmaf(kvret[n*8+v], Wkvo[v*512 + d], s);
    kvout[idx] = f2b(s);
}

// combined + LayerNorm -> 4 bf16 planes
__global__ __launch_bounds__(256)
void cmb_k(const ushort* __restrict__ pos_out, const ushort* __restrict__ kv_out,
           const float* __restrict__ xg, const float* __restrict__ phi,
           const float* __restrict__ ln_g, const float* __restrict__ ln_b,
           ushort* __restrict__ p0, ushort* __restrict__ p1,
           ushort* __restrict__ p2, ushort* __restrict__ p3)
{
    __shared__ float red[8];
    int n = blockIdx.x; int t = threadIdx.x;
    int wave = t>>6, lane = t&63;
    float v_[8]; float sum=0.f, sumsq=0.f;
    #pragma unroll
    for (int i=0;i<8;i++){
        int cidx = t + i*256;
        int seg = cidx >> 9, cc = cidx & 511;
        size_t id = (size_t)n*D_ + cc;
        float v;
        if (seg==0) v = b2f(pos_out[id]);
        else if (seg==1) v = b2f(kv_out[id]);
        else {
            float sp, cp; sincosf(phi[id], &sp, &cp);
            v = xg[id] * ((seg==2) ? cp : sp);
        }
        v_[i]=v; sum += v; sumsq = fmaf(v,v,sumsq);
    }
    #pragma unroll
    for (int off=32; off>0; off>>=1){
        sum += __shfl_xor(sum, off, 64);
        sumsq += __shfl_xor(sumsq, off, 64);
    }
    if (lane==0){ red[wave]=sum; red[wave+4]=sumsq; }
    __syncthreads();
    float s = red[0]+red[1]+red[2]+red[3];
    float q = red[4]+red[5]+red[6]+red[7];
    float mu = s * (1.0f/2048.0f);
    float var = q * (1.0f/2048.0f) - mu*mu;
    float rstd = rsqrtf(var + 1e-5f);
    #pragma unroll
    for (int i=0;i<8;i++){
        int cidx = t + i*256;
        int seg = cidx >> 9, cc = cidx & 511;
        float h = (v_[i]-mu)*rstd*ln_g[cidx] + ln_b[cidx];
        ushort* pp = (seg==0)?p0:(seg==1)?p1:(seg==2)?p2:p3;
        pp[(size_t)n*D_ + cc] = f2b(h);
    }
}

__global__ void copyx_k(const float* __restrict__ x, float* __restrict__ out, size_t n)
{
    size_t i = (size_t)blockIdx.x*256 + threadIdx.x;
    if (i < n) out[i] = x[i];
}

// ---------------- host ----------------
struct WS {
    ushort *wt_omega,*wt_mag,*wt_m1v,*wt_pi1,*wt_pi2,*wt_qoff,*wt_m1o,
           *wt_kenc,*wt_sk1,*wt_sk2,*wt_o1,*wt_o2;
    ushort *xbf,*bA,*bB,*bC,*bD,*bE,*bF;
    ushort *Qc,*Qs,*Kc,*Ks,*gvb;
    float *phi,*sgate,*rinv,*kvret;
    float *csA,*csX,*csM,*csC,*csS,*csKV;
};

static size_t ws_layout(WS& w, char* base, int NB)
{
    size_t off = 0;
    auto al = [&](size_t bytes)->char* {
        char* p = base + off; off = (off + bytes + 255) & ~(size_t)255; return p;
    };
    size_t R = (size_t)NB * L_;
    w.wt_omega=(ushort*)al(512*512*2); w.wt_mag =(ushort*)al(512*512*2);
    w.wt_m1v  =(ushort*)al(512*512*2); w.wt_pi1 =(ushort*)al(512*512*2);
    w.wt_pi2  =(ushort*)al(512*512*2); w.wt_qoff=(ushort*)al(512*512*2);
    w.wt_m1o  =(ushort*)al(512*512*2); w.wt_kenc=(ushort*)al(128*512*2);
    w.wt_sk1  =(ushort*)al(512*1024*2);w.wt_sk2 =(ushort*)al(128*512*2);
    w.wt_o1   =(ushort*)al((size_t)1024*2048*2); w.wt_o2=(ushort*)al((size_t)512*1024*2);
    w.xbf=(ushort*)al(R*512*2);
    w.bA=(ushort*)al(R*512*2); w.bB=(ushort*)al(R*512*2); w.bC=(ushort*)al(R*512*2);
    w.bD=(ushort*)al(R*512*2); w.bE=(ushort*)al(R*512*2); w.bF=(ushort*)al(R*512*2);
    w.Qc=(ushort*)al(R*128*2); w.Qs=(ushort*)al(R*128*2);
    w.Kc=(ushort*)al(R*128*2); w.Ks=(ushort*)al(R*128*2);
    w.gvb=(ushort*)al(R*8*2);
    w.phi=(float*)al(R*512*4);
    w.sgate=(float*)al(R*4); w.rinv=(float*)al(R*4); w.kvret=(float*)al(R*8*4);
    w.csA=(float*)al((size_t)NB*NC*512*4); w.csX=(float*)al((size_t)NB*NC*512*4);
    w.csM=(float*)al((size_t)NB*NC*512*4); w.csC=(float*)al((size_t)NB*NC*512*4);
    w.csS=(float*)al((size_t)NB*NC*512*4);
    w.csKV=(float*)al((size_t)NB*64*2048*4);
    return off;
}

extern "C" void kernel_launch(void* const* d_in, const int* in_sizes, int n_in,
                              void* d_out, int out_size, void* d_ws, size_t ws_size,
                              hipStream_t stream)
{
    const float* x        =(const float*)d_in[0];
    const float* W_omega  =(const float*)d_in[1];  const float* b_omega=(const float*)d_in[2];
    const float* omega_sc =(const float*)d_in[3];
    const float* W_pi1    =(const float*)d_in[4];  const float* b_pi1 =(const float*)d_in[5];
    const float* W_pi2    =(const float*)d_in[6];  const float* b_pi2 =(const float*)d_in[7];
    const float* W_m1v    =(const float*)d_in[8];  const float* b_m1v =(const float*)d_in[9];
    const float* W_m1o    =(const float*)d_in[10]; const float* b_m1o =(const float*)d_in[11];
    const float* W_mag    =(const float*)d_in[12]; const float* b_mag =(const float*)d_in[13];
    const float* mag_sc   =(const float*)d_in[14];
    const float* W_qoff   =(const float*)d_in[15]; const float* b_qoff=(const float*)d_in[16];
    const float* W_kenc   =(const float*)d_in[17]; const float* b_kenc=(const float*)d_in[18];
    const float* W_venc   =(const float*)d_in[19]; const float* b_venc=(const float*)d_in[20];
    const float* W_sk1    =(const float*)d_in[21]; const float* b_sk1 =(const float*)d_in[22];
    const float* W_sk2    =(const float*)d_in[23]; const float* b_sk2 =(const float*)d_in[24];
    const float* W_sg     =(const float*)d_in[25]; const float* b_sg  =(const float*)d_in[26];
    const float* W_kvo    =(const float*)d_in[27]; const float* b_kvo =(const float*)d_in[28];
    const float* ln_g     =(const float*)d_in[29]; const float* ln_b  =(const float*)d_in[30];
    const float* W_o1     =(const float*)d_in[31]; const float* b_o1  =(const float*)d_in[32];
    const float* W_o2     =(const float*)d_in[33]; const float* b_o2  =(const float*)d_in[34];
    float* out = (float*)d_out;

    char* wsb = (char*)d_ws;
    WS w;
    int NB = 4;
    if (ws_layout(w, wsb, 4) > ws_size) {
        NB = 2;
        if (ws_layout(w, wsb, 2) > ws_size) {
            NB = 1;
            if (ws_layout(w, wsb, 1) > ws_size) {
                copyx_k<<<dim3((unsigned)(((size_t)N_*D_ + 255)/256)), dim3(256), 0, stream>>>(x, out, (size_t)N_*D_);
                return;
            }
        }
    }

    dim3 blk(256);
    auto wt = [&](const float* W, ushort* Wt, int K, int M){
        wtrans_k<<<dim3(M/32, K/32), blk, 0, stream>>>(W, Wt, K, M);
    };
    wt(W_omega,w.wt_omega,512,512); wt(W_mag,w.wt_mag,512,512); wt(W_m1v,w.wt_m1v,512,512);
    wt(W_pi1,w.wt_pi1,512,512);     wt(W_pi2,w.wt_pi2,512,512); wt(W_qoff,w.wt_qoff,512,512);
    wt(W_m1o,w.wt_m1o,512,512);     wt(W_kenc,w.wt_kenc,512,128);
    wt(W_sk1,w.wt_sk1,1024,512);    wt(W_sk2,w.wt_sk2,512,128);
    wt(W_o1,w.wt_o1,2048,1024);     wt(W_o2,w.wt_o2,1024,512);

    const int R = NB * L_;
    auto gemm = [&](const ushort* A0,const ushort* A1,const ushort* A2,const ushort* A3,
                    const ushort* Wt,const float* bias,
                    ushort* Ob0, ushort* Ob1, float* Of, int K,int M,int act,
                    const float* colscale,const float* sscale,const ushort* mul,const float* add){
        dim3 grid(M/128, R/128);
        bgemm_k<<<grid, blk, 0, stream>>>(A0,A1,A2,A3,Wt,bias,Ob0,Ob1,Of,K,M,act,colscale,sscale,mul,add);
    };

    for (int g = 0; g < B_/NB; ++g) {
        const float* xg = x + (size_t)g*NB*LD;
        float* outg = out + (size_t)g*NB*LD;

        fconv_k<<<dim3((unsigned)((size_t)R*512/1024)), blk, 0, stream>>>(xg, w.xbf);

        gemm(w.xbf,0,0,0, w.wt_omega,b_omega, w.bA,0,0, 512,512,0, omega_sc,0,0,0); // omega
        gemm(w.xbf,0,0,0, w.wt_mag,  b_mag,   w.bB,0,0, 512,512,2, 0,mag_sc,0,0);   // magnitude
        gemm(w.xbf,0,0,0, w.wt_m1v,  b_m1v,   w.bC,0,0, 512,512,0, 0,0,w.bB,0);     // wv1
        gemm(w.xbf,0,0,0, w.wt_pi1,  b_pi1,   w.bD,0,0, 512,512,1, 0,0,0,0);        // gelu(x@W_pi1)
        gemm(w.bD,0,0,0,  w.wt_pi2,  b_pi2,   w.bE,0,0, 512,512,0, 0,0,0,0);        // phi_init
        gemm(w.xbf,0,0,0, w.wt_qoff, b_qoff,  w.bF,0,0, 512,512,0, 0,0,0,0);        // qoff
        gemm(w.xbf,0,0,0, w.wt_kenc, b_kenc,  w.Qc,w.Qs,0, 512,128,4, 0,0,0,0);     // q_cos,q_sin
        vencsg_k<<<dim3((unsigned)((size_t)R*64/256)), blk, 0, stream>>>(xg, W_venc,b_venc, W_sg,b_sg, w.gvb, w.sgate);
        gatescan_k<<<dim3(NB), blk, 0, stream>>>(w.sgate, w.rinv);

        s1a_k<<<dim3(NB*NC*2), blk, 0, stream>>>(w.bA, xg, w.csA, w.csX);
        prefix_k<<<dim3(NB*2), blk, 0, stream>>>(w.csA, w.csX, (float*)0, 2);
        s1c_k<<<dim3(NB*NC*2), blk, 0, stream>>>(w.bA, xg, w.bE, w.bB, w.bC, w.csA, w.csX, w.phi, w.bD, w.csM, w.csC, w.csS);
        prefix_k<<<dim3(NB*2), blk, 0, stream>>>(w.csM, w.csC, w.csS, 3);
        s1e_k<<<dim3(NB*NC*2), blk, 0, stream>>>(w.bB, w.bC, w.bF, w.phi, w.csM, w.csC, w.csS, w.bA); // bA = pos_ret

        gemm(w.bA,0,0,0, w.wt_m1o,b_m1o, w.bE,0,0, 512,512,0, 0,0,0,0);             // pos_out -> bE
        gemm(w.xbf,w.bD,0,0, w.wt_sk1,b_sk1, w.bB,0,0, 1024,512,1, 0,0,0,0);        // sk1g -> bB
        gemm(w.bB,0,0,0, w.wt_sk2,b_sk2, w.Kc,w.Ks,0, 512,128,4, 0,0,0,0);          // store cos/sin

        kvsum_k<<<dim3(NB*64), blk, 0, stream>>>(w.Kc, w.Ks, w.gvb, w.csKV);
        kvpfx_k<<<dim3(NB*8), blk, 0, stream>>>(w.csKV);
        kv2_k<<<dim3(64, NB), blk, 0, stream>>>(w.Qc, w.Qs, w.Kc, w.Ks, w.gvb, w.rinv, w.csKV, w.kvret);
        kvo_k<<<dim3((unsigned)((size_t)R*512/256)), blk, 0, stream>>>(w.kvret, W_kvo, b_kvo, w.bC); // kv_out -> bC

        cmb_k<<<dim3(R), blk, 0, stream>>>(w.bE, w.bC, xg, w.phi, ln_g, ln_b, w.bA, w.bB, w.bD, w.bF);
        gemm(w.bA,w.bB,w.bD,w.bF, w.wt_o1,b_o1, w.bC,w.bE,0, 2048,1024,1, 0,0,0,0); // h1 -> bC,bE
        gemm(w.bC,w.bE,0,0,      w.wt_o2,b_o2, 0,0,outg, 1024,512,0, 0,0,0,xg);     // out = x + ...
    }
}